// Round 1
// baseline (7922.063 us; speedup 1.0000x reference)
//
#include <hip/hip_runtime.h>
#include <math.h>

#define SEQ 4096
#define DIM 1024

// ---------------------------------------------------------------------------
// Kernel 1: C = X @ W   (X: SEQ x DIM, W: DIM x DIM), fp32.
// STORE_T=false: C row-major [SEQ][DIM].  STORE_T=true: store C^T [DIM][SEQ].
// Tiling: 64x64 tile, BK=16, 256 threads, 4x4 micro-tile per thread.
// ---------------------------------------------------------------------------
template <bool STORE_T>
__global__ __launch_bounds__(256) void proj_gemm(const float* __restrict__ X,
                                                 const float* __restrict__ W,
                                                 float* __restrict__ C) {
    __shared__ float As[16][64];   // [k][m]
    __shared__ float Bs[16][64];   // [k][n]

    const int tid = threadIdx.x;
    const int tx = tid & 15;       // n-group
    const int ty = tid >> 4;       // m-group
    const int m0 = blockIdx.x * 64;
    const int n0 = blockIdx.y * 64;

    float acc[4][4] = {};

    for (int k0 = 0; k0 < DIM; k0 += 16) {
        // Load A tile (64 rows x 16 k), transposed into As[k][m].
        {
            const int m  = tid >> 2;          // 0..63
            const int kq = (tid & 3) * 4;     // 0,4,8,12
            const float4 a = *reinterpret_cast<const float4*>(
                &X[(size_t)(m0 + m) * DIM + k0 + kq]);
            As[kq + 0][m] = a.x;
            As[kq + 1][m] = a.y;
            As[kq + 2][m] = a.z;
            As[kq + 3][m] = a.w;
        }
        // Load B tile (16 k x 64 n) directly.
        {
            const int kr = tid >> 4;          // 0..15
            const int n  = (tid & 15) * 4;    // 0..60
            const float4 b = *reinterpret_cast<const float4*>(
                &W[(size_t)(k0 + kr) * DIM + n0 + n]);
            *reinterpret_cast<float4*>(&Bs[kr][n]) = b;
        }
        __syncthreads();

#pragma unroll
        for (int k = 0; k < 16; ++k) {
            const float4 a4 = *reinterpret_cast<const float4*>(&As[k][ty * 4]);
            const float4 b4 = *reinterpret_cast<const float4*>(&Bs[k][tx * 4]);
            const float a[4] = {a4.x, a4.y, a4.z, a4.w};
            const float b[4] = {b4.x, b4.y, b4.z, b4.w};
#pragma unroll
            for (int i = 0; i < 4; ++i)
#pragma unroll
                for (int j = 0; j < 4; ++j) acc[i][j] += a[i] * b[j];
        }
        __syncthreads();
    }

    if (!STORE_T) {
#pragma unroll
        for (int i = 0; i < 4; ++i) {
            const float4 v = make_float4(acc[i][0], acc[i][1], acc[i][2], acc[i][3]);
            *reinterpret_cast<float4*>(
                &C[(size_t)(m0 + ty * 4 + i) * DIM + n0 + tx * 4]) = v;
        }
    } else {
        // C^T is [DIM][SEQ]: CT[n][m] = acc[i][j] with n = n0+tx*4+j, m = m0+ty*4+i
#pragma unroll
        for (int i = 0; i < 4; ++i)
#pragma unroll
            for (int j = 0; j < 4; ++j)
                C[(size_t)(n0 + tx * 4 + j) * SEQ + (m0 + ty * 4 + i)] = acc[i][j];
    }
}

// ---------------------------------------------------------------------------
// Kernel 2: flash-style attention, fp32.
//   O[r] = softmax( Q[r] . K^T / 32 ) @ V
// 8 rows per block, 256 threads, online softmax over key-chunks of 256.
//   Phase A: scores  (thread: one j, all 8 rows)
//   Phase B: team (32 threads = 1 row) online-softmax update
//   Phase C: acc update (thread: row = tid>>5, 32 contiguous d's)
// ---------------------------------------------------------------------------
__global__ __launch_bounds__(256) void attn_fused(const float* __restrict__ Q,
                                                  const float* __restrict__ KT,  // [DIM][SEQ]
                                                  const float* __restrict__ V,
                                                  float* __restrict__ O) {
    __shared__ float Qs[8][DIM];     // 32 KB
    __shared__ float Ps[8][256];     // 8 KB
    __shared__ float mrow[8], lrow[8], alphas[8];

    const int tid = threadIdx.x;
    const int r0 = blockIdx.x * 8;

    // Stage the 8 Q rows (contiguous 8192 floats) into LDS.
    {
        const float4* src = reinterpret_cast<const float4*>(Q + (size_t)r0 * DIM);
        float4* dst = reinterpret_cast<float4*>(&Qs[0][0]);
#pragma unroll
        for (int i = 0; i < 8; ++i) dst[tid + 256 * i] = src[tid + 256 * i];
    }
    if (tid < 8) {
        mrow[tid] = -INFINITY;
        lrow[tid] = 0.f;
    }
    __syncthreads();

    const int team = tid >> 5;   // row 0..7
    const int l32 = tid & 31;
    const int d0 = l32 * 32;     // this thread's 32-wide d slice

    float acc[32];
#pragma unroll
    for (int i = 0; i < 32; ++i) acc[i] = 0.f;

    for (int jb = 0; jb < SEQ; jb += 256) {
        // ---- Phase A: scores for j = jb + tid, all 8 rows ----
        float s8[8];
#pragma unroll
        for (int r = 0; r < 8; ++r) s8[r] = 0.f;
        {
            const float* KTcol = KT + jb + tid;
            for (int d = 0; d < DIM; d += 4) {
                const float k0 = KTcol[(size_t)(d + 0) * SEQ];
                const float k1 = KTcol[(size_t)(d + 1) * SEQ];
                const float k2 = KTcol[(size_t)(d + 2) * SEQ];
                const float k3 = KTcol[(size_t)(d + 3) * SEQ];
#pragma unroll
                for (int r = 0; r < 8; ++r) {
                    const float4 q4 = *reinterpret_cast<const float4*>(&Qs[r][d]);
                    s8[r] += q4.x * k0 + q4.y * k1 + q4.z * k2 + q4.w * k3;
                }
            }
        }

        __syncthreads();   // previous Phase C done reading Ps
#pragma unroll
        for (int r = 0; r < 8; ++r) Ps[r][tid] = s8[r] * 0.03125f;  // 1/sqrt(1024)
        __syncthreads();

        // ---- Phase B: per-row online softmax (team = one row) ----
        {
            float loc[8];
#pragma unroll
            for (int k = 0; k < 8; ++k) loc[k] = Ps[team][l32 + 32 * k];
            float mx = loc[0];
#pragma unroll
            for (int k = 1; k < 8; ++k) mx = fmaxf(mx, loc[k]);
#pragma unroll
            for (int m = 16; m >= 1; m >>= 1) mx = fmaxf(mx, __shfl_xor(mx, m));

            const float mold = mrow[team];
            const float mnew = fmaxf(mold, mx);
            const float alpha = __expf(mold - mnew);   // 0 on first chunk
            float sum = 0.f;
#pragma unroll
            for (int k = 0; k < 8; ++k) {
                const float p = __expf(loc[k] - mnew);
                Ps[team][l32 + 32 * k] = p;
                sum += p;
            }
#pragma unroll
            for (int m = 16; m >= 1; m >>= 1) sum += __shfl_xor(sum, m);

            if (l32 == 0) {
                mrow[team] = mnew;
                alphas[team] = alpha;
                lrow[team] = lrow[team] * alpha + sum;
            }
        }
        __syncthreads();

        // ---- Phase C: acc = acc*alpha + P @ V-chunk ----
        {
            const float a = alphas[team];
#pragma unroll
            for (int i = 0; i < 32; ++i) acc[i] *= a;
            for (int j = 0; j < 256; ++j) {
                const float p = Ps[team][j];
                const float* vrow = V + (size_t)(jb + j) * DIM + d0;
#pragma unroll
                for (int q = 0; q < 8; ++q) {
                    const float4 v4 = *reinterpret_cast<const float4*>(vrow + q * 4);
                    acc[q * 4 + 0] += p * v4.x;
                    acc[q * 4 + 1] += p * v4.y;
                    acc[q * 4 + 2] += p * v4.z;
                    acc[q * 4 + 3] += p * v4.w;
                }
            }
        }
    }

    // ---- Final: divide by l and store ----
    {
        const float rl = 1.f / lrow[team];
        float* orow = O + (size_t)(r0 + team) * DIM + d0;
#pragma unroll
        for (int q = 0; q < 8; ++q) {
            const float4 v = make_float4(acc[q * 4 + 0] * rl, acc[q * 4 + 1] * rl,
                                         acc[q * 4 + 2] * rl, acc[q * 4 + 3] * rl);
            *reinterpret_cast<float4*>(orow + q * 4) = v;
        }
    }
}

// ---------------------------------------------------------------------------
extern "C" void kernel_launch(void* const* d_in, const int* in_sizes, int n_in,
                              void* d_out, int out_size, void* d_ws, size_t ws_size,
                              hipStream_t stream) {
    const float* x  = (const float*)d_in[0];
    const float* wq = (const float*)d_in[1];
    const float* wk = (const float*)d_in[2];
    const float* wv = (const float*)d_in[3];
    float* O = (float*)d_out;

    // Workspace layout (fp32): Q [SEQ*DIM], KT [DIM*SEQ], V [SEQ*DIM] = 48 MB
    float* Qw  = (float*)d_ws;
    float* KTw = Qw + (size_t)SEQ * DIM;
    float* Vw  = KTw + (size_t)SEQ * DIM;

    const dim3 ggrid(SEQ / 64, DIM / 64);
    proj_gemm<false><<<ggrid, 256, 0, stream>>>(x, wq, Qw);
    proj_gemm<true><<<ggrid, 256, 0, stream>>>(x, wk, KTw);
    proj_gemm<false><<<ggrid, 256, 0, stream>>>(x, wv, Vw);

    attn_fused<<<SEQ / 8, 256, 0, stream>>>(Qw, KTw, Vw, O);
}

// Round 3
// 452.592 us; speedup vs baseline: 17.5038x; 17.5038x over previous
//
#include <hip/hip_runtime.h>
#include <math.h>

#define SEQ 4096
#define DIM 1024

typedef __bf16 bf16;
typedef __bf16 bf16x8 __attribute__((ext_vector_type(8)));
typedef __bf16 bf16x4 __attribute__((ext_vector_type(4)));
typedef float f32x4 __attribute__((ext_vector_type(4)));

#define GLOAD_LDS16(g, l)                                              \
    __builtin_amdgcn_global_load_lds(                                  \
        (const __attribute__((address_space(1))) void*)(g),            \
        (__attribute__((address_space(3))) void*)(l), 16, 0, 0)

// ---------------------------------------------------------------------------
// Split f32 -> (hi, lo) bf16, vectorized by 4.
// ---------------------------------------------------------------------------
__global__ __launch_bounds__(256) void split_f32(const float* __restrict__ in,
                                                 bf16* __restrict__ hi,
                                                 bf16* __restrict__ lo, int n4) {
    const int i = blockIdx.x * 256 + threadIdx.x;
    if (i >= n4) return;
    const float4 v = ((const float4*)in)[i];
    const float vv[4] = {v.x, v.y, v.z, v.w};
    bf16x4 h, l;
#pragma unroll
    for (int q = 0; q < 4; ++q) {
        const bf16 hq = (bf16)vv[q];
        h[q] = hq;
        l[q] = (bf16)(vv[q] - (float)hq);
    }
    ((bf16x4*)hi)[i] = h;
    ((bf16x4*)lo)[i] = l;
}

// ---------------------------------------------------------------------------
// Transpose-convert W [DIM][DIM] f32 -> W^T bf16 (hi, and lo if SPLIT).
// 32x32 LDS tile.
// ---------------------------------------------------------------------------
template <bool SPLIT>
__global__ __launch_bounds__(256) void wtrans(const float* __restrict__ W,
                                              bf16* __restrict__ hiT,
                                              bf16* __restrict__ loT) {
    __shared__ float tile[32][33];
    const int tid = threadIdx.x;
    const int r0 = blockIdx.x * 32;  // W row (k)
    const int c0 = blockIdx.y * 32;  // W col (n)
    {
        const int r = tid >> 3, c = (tid & 7) * 4;
        const float4 v = *(const float4*)&W[(size_t)(r0 + r) * DIM + c0 + c];
        tile[r][c + 0] = v.x;
        tile[r][c + 1] = v.y;
        tile[r][c + 2] = v.z;
        tile[r][c + 3] = v.w;
    }
    __syncthreads();
    {
        const int n = tid >> 3;
        const int k = (tid & 7) * 4;
        bf16x4 h, l;
#pragma unroll
        for (int q = 0; q < 4; ++q) {
            const float x = tile[k + q][n];
            const bf16 hq = (bf16)x;
            h[q] = hq;
            if (SPLIT) l[q] = (bf16)(x - (float)hq);
        }
        *(bf16x4*)&hiT[(size_t)(c0 + n) * DIM + r0 + k] = h;
        if (SPLIT) *(bf16x4*)&loT[(size_t)(c0 + n) * DIM + r0 + k] = l;
    }
}

// ---------------------------------------------------------------------------
// MFMA GEMM: C(MxN) = sum_p A_p (row-major [M][K]) @ B_p^T (row-major [N][K])
// 128x128 tile, 256 threads (4 waves, 2x2), 16x16x32 bf16 MFMA, BK=32,
// global_load_lds staging, 2-barrier loop (m97 structure).
// Epilogues: 0 = f32 (scaled), 1 = split hi/lo bf16, 2 = transposed bf16.
// ---------------------------------------------------------------------------
#define EPI_F32 0
#define EPI_SPLIT 1
#define EPI_TRANS 2

template <int EPI, int NPAIR>
__global__ __launch_bounds__(256) void gemm_bt(
    const bf16* __restrict__ A0, const bf16* __restrict__ B0,
    const bf16* __restrict__ A1, const bf16* __restrict__ B1,
    const bf16* __restrict__ A2, const bf16* __restrict__ B2,
    const bf16* __restrict__ A3, const bf16* __restrict__ B3,
    int N, int K, float scale, void* out0, void* out1) {
    __shared__ __align__(16) bf16 As[128 * 32];
    __shared__ __align__(16) bf16 Bs[128 * 32];

    const int tid = threadIdx.x;
    const int m0 = blockIdx.x * 128;
    const int n0 = blockIdx.y * 128;
    const int lane = tid & 63;
    const int wid = tid >> 6;
    const int wr = wid >> 1, wc = wid & 1;

    f32x4 acc[4][4];
#pragma unroll
    for (int i = 0; i < 4; ++i)
#pragma unroll
        for (int j = 0; j < 4; ++j) acc[i][j] = (f32x4){0.f, 0.f, 0.f, 0.f};

    const bf16* APs[4] = {A0, A1, A2, A3};
    const bf16* BPs[4] = {B0, B1, B2, B3};

    const int sr = tid >> 2;         // staging row within 64-row half
    const int sk = (tid & 3) * 8;    // staging k offset
    bf16* asDst = As + wid * 512;    // wave-uniform LDS dest (elements)
    bf16* bsDst = Bs + wid * 512;

    const int ra = lane & 15;            // fragment row
    const int ka = (lane >> 4) * 8;      // fragment k offset

#pragma unroll
    for (int p = 0; p < NPAIR; ++p) {
        const bf16* __restrict__ Ap = APs[p];
        const bf16* __restrict__ Bp = BPs[p];
        for (int k0 = 0; k0 < K; k0 += 32) {
            GLOAD_LDS16(Ap + (size_t)(m0 + sr) * K + k0 + sk, asDst);
            GLOAD_LDS16(Ap + (size_t)(m0 + 64 + sr) * K + k0 + sk, asDst + 2048);
            GLOAD_LDS16(Bp + (size_t)(n0 + sr) * K + k0 + sk, bsDst);
            GLOAD_LDS16(Bp + (size_t)(n0 + 64 + sr) * K + k0 + sk, bsDst + 2048);
            __syncthreads();

            bf16x8 af[4], bfr[4];
#pragma unroll
            for (int i = 0; i < 4; ++i)
                af[i] = *(const bf16x8*)(As + (wr * 64 + i * 16 + ra) * 32 + ka);
#pragma unroll
            for (int j = 0; j < 4; ++j)
                bfr[j] = *(const bf16x8*)(Bs + (wc * 64 + j * 16 + ra) * 32 + ka);
#pragma unroll
            for (int i = 0; i < 4; ++i)
#pragma unroll
                for (int j = 0; j < 4; ++j)
                    acc[i][j] = __builtin_amdgcn_mfma_f32_16x16x32_bf16(
                        af[i], bfr[j], acc[i][j], 0, 0, 0);
            __syncthreads();
        }
    }

    // Epilogue. acc[i][j][q] = C[m0+wr*64+i*16+(lane>>4)*4+q][n0+wc*64+j*16+(lane&15)]
    const int row0 = m0 + wr * 64 + (lane >> 4) * 4;
    const int col0 = n0 + wc * 64 + (lane & 15);

    if (EPI == EPI_F32) {
        float* O = (float*)out0;
#pragma unroll
        for (int i = 0; i < 4; ++i)
#pragma unroll
            for (int j = 0; j < 4; ++j)
#pragma unroll
                for (int q = 0; q < 4; ++q)
                    O[(size_t)(row0 + i * 16 + q) * N + col0 + j * 16] =
                        acc[i][j][q] * scale;
    } else if (EPI == EPI_SPLIT) {
        bf16* Hi = (bf16*)out0;
        bf16* Lo = (bf16*)out1;
#pragma unroll
        for (int i = 0; i < 4; ++i)
#pragma unroll
            for (int j = 0; j < 4; ++j)
#pragma unroll
                for (int q = 0; q < 4; ++q) {
                    const float x = acc[i][j][q];
                    const bf16 h = (bf16)x;
                    const size_t idx = (size_t)(row0 + i * 16 + q) * N + col0 + j * 16;
                    Hi[idx] = h;
                    Lo[idx] = (bf16)(x - (float)h);
                }
    } else {  // EPI_TRANS: out[col][row], col-major over SEQ rows
        bf16* OT = (bf16*)out0;
#pragma unroll
        for (int i = 0; i < 4; ++i)
#pragma unroll
            for (int j = 0; j < 4; ++j) {
                bf16x4 v;
#pragma unroll
                for (int q = 0; q < 4; ++q) v[q] = (bf16)acc[i][j][q];
                *(bf16x4*)&OT[(size_t)(col0 + j * 16) * SEQ + row0 + i * 16] = v;
            }
    }
}

// ---------------------------------------------------------------------------
// Row softmax: S (f32 [SEQ][SEQ], already scaled) -> P (bf16, normalized).
// One block (256 thr) per row; 16 elements/thread in registers.
// ---------------------------------------------------------------------------
__global__ __launch_bounds__(256) void softmax_rows(const float* __restrict__ S,
                                                    bf16* __restrict__ P) {
    __shared__ float red[8];
    const int tid = threadIdx.x;
    const size_t row = blockIdx.x;
    const float4* s4 = (const float4*)(S + row * SEQ);

    float4 v[4];
    float mx = -1e30f;
#pragma unroll
    for (int c = 0; c < 4; ++c) {
        v[c] = s4[c * 256 + tid];
        mx = fmaxf(mx, fmaxf(fmaxf(v[c].x, v[c].y), fmaxf(v[c].z, v[c].w)));
    }
#pragma unroll
    for (int m = 32; m >= 1; m >>= 1) mx = fmaxf(mx, __shfl_xor(mx, m));
    if ((tid & 63) == 0) red[tid >> 6] = mx;
    __syncthreads();
    mx = fmaxf(fmaxf(red[0], red[1]), fmaxf(red[2], red[3]));

    float e[16];
    float sum = 0.f;
#pragma unroll
    for (int c = 0; c < 4; ++c) {
        e[c * 4 + 0] = __expf(v[c].x - mx);
        e[c * 4 + 1] = __expf(v[c].y - mx);
        e[c * 4 + 2] = __expf(v[c].z - mx);
        e[c * 4 + 3] = __expf(v[c].w - mx);
        sum += e[c * 4] + e[c * 4 + 1] + e[c * 4 + 2] + e[c * 4 + 3];
    }
#pragma unroll
    for (int m = 32; m >= 1; m >>= 1) sum += __shfl_xor(sum, m);
    if ((tid & 63) == 0) red[4 + (tid >> 6)] = sum;
    __syncthreads();
    sum = red[4] + red[5] + red[6] + red[7];
    const float inv = 1.f / sum;

    bf16* prow = P + row * SEQ;
#pragma unroll
    for (int c = 0; c < 4; ++c) {
        bf16x4 o;
#pragma unroll
        for (int q = 0; q < 4; ++q) o[q] = (bf16)(e[c * 4 + q] * inv);
        ((bf16x4*)prow)[c * 256 + tid] = o;
    }
}

// ---------------------------------------------------------------------------
extern "C" void kernel_launch(void* const* d_in, const int* in_sizes, int n_in,
                              void* d_out, int out_size, void* d_ws, size_t ws_size,
                              hipStream_t stream) {
    const float* x  = (const float*)d_in[0];
    const float* wq = (const float*)d_in[1];
    const float* wk = (const float*)d_in[2];
    const float* wv = (const float*)d_in[3];
    float* O = (float*)d_out;

    char* ws = (char*)d_ws;
    const size_t MB = 1024 * 1024;
    // Lifetime-overlaid layout (104 MB total):
    bf16* Qhi = (bf16*)(ws + 0 * MB);     // phase 2 -> 3
    bf16* Qlo = (bf16*)(ws + 8 * MB);
    bf16* Khi = (bf16*)(ws + 16 * MB);
    bf16* Klo = (bf16*)(ws + 24 * MB);
    bf16* VT  = (bf16*)(ws + 32 * MB);    // phase 2 -> 5
    float* S  = (float*)(ws + 40 * MB);   // phase 3 -> 4 (64 MB)
    bf16* P   = (bf16*)(ws + 0 * MB);     // phase 4 -> 5 (overlays Q/K)
    // converts live inside the S region (die before S is written):
    bf16* Xhi   = (bf16*)(ws + 40 * MB);
    bf16* Xlo   = (bf16*)(ws + 48 * MB);
    bf16* WqhiT = (bf16*)(ws + 56 * MB);
    bf16* WqloT = (bf16*)(ws + 58 * MB);
    bf16* WkhiT = (bf16*)(ws + 60 * MB);
    bf16* WkloT = (bf16*)(ws + 62 * MB);
    bf16* WvT   = (bf16*)(ws + 64 * MB);

    // Phase 1: converts
    split_f32<<<(SEQ * DIM / 4 + 255) / 256, 256, 0, stream>>>(x, Xhi, Xlo,
                                                               SEQ * DIM / 4);
    const dim3 wgrid(DIM / 32, DIM / 32);
    wtrans<true><<<wgrid, 256, 0, stream>>>(wq, WqhiT, WqloT);
    wtrans<true><<<wgrid, 256, 0, stream>>>(wk, WkhiT, WkloT);
    wtrans<false><<<wgrid, 256, 0, stream>>>(wv, WvT, nullptr);

    // Phase 2: projections
    const dim3 pgrid(SEQ / 128, DIM / 128);
    gemm_bt<EPI_SPLIT, 3><<<pgrid, 256, 0, stream>>>(
        Xhi, WqhiT, Xhi, WqloT, Xlo, WqhiT, nullptr, nullptr,
        DIM, DIM, 1.f, Qhi, Qlo);
    gemm_bt<EPI_SPLIT, 3><<<pgrid, 256, 0, stream>>>(
        Xhi, WkhiT, Xhi, WkloT, Xlo, WkhiT, nullptr, nullptr,
        DIM, DIM, 1.f, Khi, Klo);
    gemm_bt<EPI_TRANS, 1><<<pgrid, 256, 0, stream>>>(
        Xhi, WvT, nullptr, nullptr, nullptr, nullptr, nullptr, nullptr,
        DIM, DIM, 1.f, VT, nullptr);

    // Phase 3: S = (Q @ K^T) / 32, 4-way split product
    const dim3 sgrid(SEQ / 128, SEQ / 128);
    gemm_bt<EPI_F32, 4><<<sgrid, 256, 0, stream>>>(
        Qhi, Khi, Qhi, Klo, Qlo, Khi, Qlo, Klo,
        SEQ, DIM, 0.03125f, S, nullptr);

    // Phase 4: row softmax -> P (bf16, normalized)
    softmax_rows<<<SEQ, 256, 0, stream>>>(S, P);

    // Phase 5: O = P @ V  (B^T = VT)
    gemm_bt<EPI_F32, 1><<<pgrid, 256, 0, stream>>>(
        P, VT, nullptr, nullptr, nullptr, nullptr, nullptr, nullptr,
        DIM, SEQ, 1.f, O, nullptr);
}

// Round 4
// 370.946 us; speedup vs baseline: 21.3564x; 1.2201x over previous
//
#include <hip/hip_runtime.h>
#include <math.h>

#define SEQ 4096
#define DIM 1024

typedef __bf16 bf16;
typedef __bf16 bf16x8 __attribute__((ext_vector_type(8)));
typedef __bf16 bf16x4 __attribute__((ext_vector_type(4)));
typedef float f32x4 __attribute__((ext_vector_type(4)));

#define GLOAD_LDS16(g, l)                                              \
    __builtin_amdgcn_global_load_lds(                                  \
        (const __attribute__((address_space(1))) void*)(g),            \
        (__attribute__((address_space(3))) void*)(l), 16, 0, 0)

// ---------------------------------------------------------------------------
// Split f32 -> (hi, lo) bf16, vectorized by 4.
// ---------------------------------------------------------------------------
__global__ __launch_bounds__(256) void split_f32(const float* __restrict__ in,
                                                 bf16* __restrict__ hi,
                                                 bf16* __restrict__ lo, int n4) {
    const int i = blockIdx.x * 256 + threadIdx.x;
    if (i >= n4) return;
    const float4 v = ((const float4*)in)[i];
    const float vv[4] = {v.x, v.y, v.z, v.w};
    bf16x4 h, l;
#pragma unroll
    for (int q = 0; q < 4; ++q) {
        const bf16 hq = (bf16)vv[q];
        h[q] = hq;
        l[q] = (bf16)(vv[q] - (float)hq);
    }
    ((bf16x4*)hi)[i] = h;
    ((bf16x4*)lo)[i] = l;
}

// ---------------------------------------------------------------------------
// Transpose-convert W [DIM][DIM] f32 -> W^T bf16 (hi, and lo if SPLIT).
// ---------------------------------------------------------------------------
template <bool SPLIT>
__global__ __launch_bounds__(256) void wtrans(const float* __restrict__ W,
                                              bf16* __restrict__ hiT,
                                              bf16* __restrict__ loT) {
    __shared__ float tile[32][33];
    const int tid = threadIdx.x;
    const int r0 = blockIdx.x * 32;  // W row (k)
    const int c0 = blockIdx.y * 32;  // W col (n)
    {
        const int r = tid >> 3, c = (tid & 7) * 4;
        const float4 v = *(const float4*)&W[(size_t)(r0 + r) * DIM + c0 + c];
        tile[r][c + 0] = v.x;
        tile[r][c + 1] = v.y;
        tile[r][c + 2] = v.z;
        tile[r][c + 3] = v.w;
    }
    __syncthreads();
    {
        const int n = tid >> 3;
        const int k = (tid & 7) * 4;
        bf16x4 h, l;
#pragma unroll
        for (int q = 0; q < 4; ++q) {
            const float x = tile[k + q][n];
            const bf16 hq = (bf16)x;
            h[q] = hq;
            if (SPLIT) l[q] = (bf16)(x - (float)hq);
        }
        *(bf16x4*)&hiT[(size_t)(c0 + n) * DIM + r0 + k] = h;
        if (SPLIT) *(bf16x4*)&loT[(size_t)(c0 + n) * DIM + r0 + k] = l;
    }
}

// ---------------------------------------------------------------------------
// 128x128 MFMA GEMM (m97 structure) — used for projections and PV.
// C(MxN) = sum_p A_p [M][K] @ B_p^T [N][K].
// ---------------------------------------------------------------------------
#define EPI_F32 0
#define EPI_SPLIT 1
#define EPI_TRANS 2

template <int EPI, int NPAIR>
__global__ __launch_bounds__(256) void gemm_bt(
    const bf16* __restrict__ A0, const bf16* __restrict__ B0,
    const bf16* __restrict__ A1, const bf16* __restrict__ B1,
    const bf16* __restrict__ A2, const bf16* __restrict__ B2,
    int N, int K, float scale, void* out0, void* out1) {
    __shared__ __align__(16) bf16 As[128 * 32];
    __shared__ __align__(16) bf16 Bs[128 * 32];

    const int tid = threadIdx.x;
    const int m0 = blockIdx.x * 128;
    const int n0 = blockIdx.y * 128;
    const int lane = tid & 63;
    const int wid = tid >> 6;
    const int wr = wid >> 1, wc = wid & 1;

    f32x4 acc[4][4];
#pragma unroll
    for (int i = 0; i < 4; ++i)
#pragma unroll
        for (int j = 0; j < 4; ++j) acc[i][j] = (f32x4){0.f, 0.f, 0.f, 0.f};

    const bf16* APs[3] = {A0, A1, A2};
    const bf16* BPs[3] = {B0, B1, B2};

    const int sr = tid >> 2;
    const int sk = (tid & 3) * 8;
    bf16* asDst = As + wid * 512;
    bf16* bsDst = Bs + wid * 512;

    const int ra = lane & 15;
    const int ka = (lane >> 4) * 8;

#pragma unroll
    for (int p = 0; p < NPAIR; ++p) {
        const bf16* __restrict__ Ap = APs[p];
        const bf16* __restrict__ Bp = BPs[p];
        for (int k0 = 0; k0 < K; k0 += 32) {
            GLOAD_LDS16(Ap + (size_t)(m0 + sr) * K + k0 + sk, asDst);
            GLOAD_LDS16(Ap + (size_t)(m0 + 64 + sr) * K + k0 + sk, asDst + 2048);
            GLOAD_LDS16(Bp + (size_t)(n0 + sr) * K + k0 + sk, bsDst);
            GLOAD_LDS16(Bp + (size_t)(n0 + 64 + sr) * K + k0 + sk, bsDst + 2048);
            __syncthreads();

            bf16x8 af[4], bfr[4];
#pragma unroll
            for (int i = 0; i < 4; ++i)
                af[i] = *(const bf16x8*)(As + (wr * 64 + i * 16 + ra) * 32 + ka);
#pragma unroll
            for (int j = 0; j < 4; ++j)
                bfr[j] = *(const bf16x8*)(Bs + (wc * 64 + j * 16 + ra) * 32 + ka);
#pragma unroll
            for (int i = 0; i < 4; ++i)
#pragma unroll
                for (int j = 0; j < 4; ++j)
                    acc[i][j] = __builtin_amdgcn_mfma_f32_16x16x32_bf16(
                        af[i], bfr[j], acc[i][j], 0, 0, 0);
            __syncthreads();
        }
    }

    const int row0 = m0 + wr * 64 + (lane >> 4) * 4;
    const int col0 = n0 + wc * 64 + (lane & 15);

    if (EPI == EPI_F32) {
        float* O = (float*)out0;
#pragma unroll
        for (int i = 0; i < 4; ++i)
#pragma unroll
            for (int j = 0; j < 4; ++j)
#pragma unroll
                for (int q = 0; q < 4; ++q)
                    O[(size_t)(row0 + i * 16 + q) * N + col0 + j * 16] =
                        acc[i][j][q] * scale;
    } else if (EPI == EPI_SPLIT) {
        bf16* Hi = (bf16*)out0;
        bf16* Lo = (bf16*)out1;
#pragma unroll
        for (int i = 0; i < 4; ++i)
#pragma unroll
            for (int j = 0; j < 4; ++j)
#pragma unroll
                for (int q = 0; q < 4; ++q) {
                    const float x = acc[i][j][q];
                    const bf16 h = (bf16)x;
                    const size_t idx = (size_t)(row0 + i * 16 + q) * N + col0 + j * 16;
                    Hi[idx] = h;
                    Lo[idx] = (bf16)(x - (float)h);
                }
    } else {  // EPI_TRANS
        bf16* OT = (bf16*)out0;
#pragma unroll
        for (int i = 0; i < 4; ++i)
#pragma unroll
            for (int j = 0; j < 4; ++j) {
                bf16x4 v;
#pragma unroll
                for (int q = 0; q < 4; ++q) v[q] = (bf16)acc[i][j][q];
                *(bf16x4*)&OT[(size_t)(col0 + j * 16) * SEQ + row0 + i * 16] = v;
            }
    }
}

// ---------------------------------------------------------------------------
// 256x256 MFMA GEMM for QK^T: 512 thr (8 waves 2x4), BK=64, double-buffered
// LDS with counted-vmcnt prefetch (never vmcnt(0) in loop), XOR-swizzled LDS
// (linear gload_lds dest + pre-swizzled global source + swizzled read),
// XCD-aware block swizzle. C = sum_p A_p @ B_p^T, f32 out, scaled.
// ---------------------------------------------------------------------------
template <int NPAIR>
__global__ __launch_bounds__(512, 2) void gemm256(
    const bf16* __restrict__ A0, const bf16* __restrict__ B0,
    const bf16* __restrict__ A1, const bf16* __restrict__ B1,
    const bf16* __restrict__ A2, const bf16* __restrict__ B2,
    int N, int K, float scale, float* __restrict__ out) {
    __shared__ __align__(16) bf16 As[2][256 * 64];   // 64 KB
    __shared__ __align__(16) bf16 Bs[2][256 * 64];   // 64 KB

    const int tid = threadIdx.x;
    const int lane = tid & 63;
    const int wid = tid >> 6;       // 0..7
    const int wr = wid >> 2;        // 0..1 (M half)
    const int wc = wid & 3;         // 0..3 (N quarter)

    // XCD swizzle: grid is 256 blocks (16x16), 256 % 8 == 0 -> simple remap.
    const int wg = (blockIdx.x & 7) * 32 + (blockIdx.x >> 3);
    const int m0 = (wg >> 4) * 256;
    const int n0 = (wg & 15) * 256;

    const bf16* APs[3] = {A0, A1, A2};
    const bf16* BPs[3] = {B0, B1, B2};
    const int ktiles = K / 64;
    const int nt = NPAIR * ktiles;

    f32x4 acc[8][4];
#pragma unroll
    for (int i = 0; i < 8; ++i)
#pragma unroll
        for (int j = 0; j < 4; ++j) acc[i][j] = (f32x4){0.f, 0.f, 0.f, 0.f};

    // Stage one 256x64 K-tile of A and B into buffer b (8 gload_lds/thread).
    // LDS dest is linear; global source col is XOR-pre-swizzled so that the
    // swizzled read below sees the right data (involution both sides).
    auto STAGE = [&](int t, int b) {
        const bf16* Ap = APs[t >> 4];   // ktiles == 16
        const bf16* Bp = BPs[t >> 4];
        const int k0 = (t & 15) * 64;
#pragma unroll
        for (int L = 0; L < 4; ++L) {
            const int idx = L * 512 + tid;          // 16B slot index
            const int row = idx >> 3;               // 0..255
            const int sc = ((idx & 7) * 16) ^ ((row & 7) << 4);  // src col-byte
            const int ldsu = (L * 512 + (tid & ~63)) * 8;        // uniform elems
            GLOAD_LDS16(Ap + (size_t)(m0 + row) * K + k0 + (sc >> 1),
                        &As[b][ldsu]);
            GLOAD_LDS16(Bp + (size_t)(n0 + row) * K + k0 + (sc >> 1),
                        &Bs[b][ldsu]);
        }
    };

    STAGE(0, 0);

    for (int t = 0; t < nt; ++t) {
        const int cur = t & 1;
        // Barrier A: all waves finished reading buf cur^1 (iter t-1 body).
        __builtin_amdgcn_s_barrier();
        asm volatile("" ::: "memory");
        if (t + 1 < nt) {
            STAGE(t + 1, cur ^ 1);
            asm volatile("s_waitcnt vmcnt(8)" ::: "memory");  // STAGE(t) done
        } else {
            asm volatile("s_waitcnt vmcnt(0)" ::: "memory");
        }
        // Barrier B: everyone's STAGE(t) writes visible.
        __builtin_amdgcn_s_barrier();
        asm volatile("" ::: "memory");

#pragma unroll
        for (int kk = 0; kk < 2; ++kk) {
            const int cb = kk * 64 + (lane >> 4) * 16;  // col-byte of fragment
            bf16x8 af[8], bv[4];
#pragma unroll
            for (int i = 0; i < 8; ++i) {
                const int r = wr * 128 + i * 16 + (lane & 15);
                af[i] = *(const bf16x8*)(&As[cur][r * 64 +
                                                  ((cb ^ ((r & 7) << 4)) >> 1)]);
            }
#pragma unroll
            for (int j = 0; j < 4; ++j) {
                const int r = wc * 64 + j * 16 + (lane & 15);
                bv[j] = *(const bf16x8*)(&Bs[cur][r * 64 +
                                                  ((cb ^ ((r & 7) << 4)) >> 1)]);
            }
            __builtin_amdgcn_s_setprio(1);
#pragma unroll
            for (int i = 0; i < 8; ++i)
#pragma unroll
                for (int j = 0; j < 4; ++j)
                    acc[i][j] = __builtin_amdgcn_mfma_f32_16x16x32_bf16(
                        af[i], bv[j], acc[i][j], 0, 0, 0);
            __builtin_amdgcn_s_setprio(0);
        }
    }

    // Epilogue: C[m][n] f32, scaled.
    const int row0 = m0 + wr * 128 + (lane >> 4) * 4;
    const int col0 = n0 + wc * 64 + (lane & 15);
#pragma unroll
    for (int i = 0; i < 8; ++i)
#pragma unroll
        for (int j = 0; j < 4; ++j)
#pragma unroll
            for (int q = 0; q < 4; ++q)
                out[(size_t)(row0 + i * 16 + q) * N + col0 + j * 16] =
                    acc[i][j][q] * scale;
}

// ---------------------------------------------------------------------------
// Row softmax: S (f32 [SEQ][SEQ], already scaled) -> P (bf16, normalized).
// ---------------------------------------------------------------------------
__global__ __launch_bounds__(256) void softmax_rows(const float* __restrict__ S,
                                                    bf16* __restrict__ P) {
    __shared__ float red[8];
    const int tid = threadIdx.x;
    const size_t row = blockIdx.x;
    const float4* s4 = (const float4*)(S + row * SEQ);

    float4 v[4];
    float mx = -1e30f;
#pragma unroll
    for (int c = 0; c < 4; ++c) {
        v[c] = s4[c * 256 + tid];
        mx = fmaxf(mx, fmaxf(fmaxf(v[c].x, v[c].y), fmaxf(v[c].z, v[c].w)));
    }
#pragma unroll
    for (int m = 32; m >= 1; m >>= 1) mx = fmaxf(mx, __shfl_xor(mx, m));
    if ((tid & 63) == 0) red[tid >> 6] = mx;
    __syncthreads();
    mx = fmaxf(fmaxf(red[0], red[1]), fmaxf(red[2], red[3]));

    float e[16];
    float sum = 0.f;
#pragma unroll
    for (int c = 0; c < 4; ++c) {
        e[c * 4 + 0] = __expf(v[c].x - mx);
        e[c * 4 + 1] = __expf(v[c].y - mx);
        e[c * 4 + 2] = __expf(v[c].z - mx);
        e[c * 4 + 3] = __expf(v[c].w - mx);
        sum += e[c * 4] + e[c * 4 + 1] + e[c * 4 + 2] + e[c * 4 + 3];
    }
#pragma unroll
    for (int m = 32; m >= 1; m >>= 1) sum += __shfl_xor(sum, m);
    if ((tid & 63) == 0) red[4 + (tid >> 6)] = sum;
    __syncthreads();
    sum = red[4] + red[5] + red[6] + red[7];
    const float inv = 1.f / sum;

    bf16* prow = P + row * SEQ;
#pragma unroll
    for (int c = 0; c < 4; ++c) {
        bf16x4 o;
#pragma unroll
        for (int q = 0; q < 4; ++q) o[q] = (bf16)(e[c * 4 + q] * inv);
        ((bf16x4*)prow)[c * 256 + tid] = o;
    }
}

// ---------------------------------------------------------------------------
extern "C" void kernel_launch(void* const* d_in, const int* in_sizes, int n_in,
                              void* d_out, int out_size, void* d_ws, size_t ws_size,
                              hipStream_t stream) {
    const float* x  = (const float*)d_in[0];
    const float* wq = (const float*)d_in[1];
    const float* wk = (const float*)d_in[2];
    const float* wv = (const float*)d_in[3];
    float* O = (float*)d_out;

    char* ws = (char*)d_ws;
    const size_t MB = 1024 * 1024;
    bf16* Qhi = (bf16*)(ws + 0 * MB);
    bf16* Qlo = (bf16*)(ws + 8 * MB);
    bf16* Khi = (bf16*)(ws + 16 * MB);
    bf16* Klo = (bf16*)(ws + 24 * MB);
    bf16* VT  = (bf16*)(ws + 32 * MB);
    float* S  = (float*)(ws + 40 * MB);   // 64 MB
    bf16* P   = (bf16*)(ws + 0 * MB);     // overlays dead Q/K
    bf16* Xhi   = (bf16*)(ws + 40 * MB);  // converts die before S written
    bf16* Xlo   = (bf16*)(ws + 48 * MB);
    bf16* WqhiT = (bf16*)(ws + 56 * MB);
    bf16* WqloT = (bf16*)(ws + 58 * MB);
    bf16* WkhiT = (bf16*)(ws + 60 * MB);
    bf16* WkloT = (bf16*)(ws + 62 * MB);
    bf16* WvT   = (bf16*)(ws + 64 * MB);

    split_f32<<<(SEQ * DIM / 4 + 255) / 256, 256, 0, stream>>>(x, Xhi, Xlo,
                                                               SEQ * DIM / 4);
    const dim3 wgrid(DIM / 32, DIM / 32);
    wtrans<true><<<wgrid, 256, 0, stream>>>(wq, WqhiT, WqloT);
    wtrans<true><<<wgrid, 256, 0, stream>>>(wk, WkhiT, WkloT);
    wtrans<false><<<wgrid, 256, 0, stream>>>(wv, WvT, nullptr);

    const dim3 pgrid(SEQ / 128, DIM / 128);
    gemm_bt<EPI_SPLIT, 3><<<pgrid, 256, 0, stream>>>(
        Xhi, WqhiT, Xhi, WqloT, Xlo, WqhiT, DIM, DIM, 1.f, Qhi, Qlo);
    gemm_bt<EPI_SPLIT, 3><<<pgrid, 256, 0, stream>>>(
        Xhi, WkhiT, Xhi, WkloT, Xlo, WkhiT, DIM, DIM, 1.f, Khi, Klo);
    gemm_bt<EPI_TRANS, 1><<<pgrid, 256, 0, stream>>>(
        Xhi, WvT, nullptr, nullptr, nullptr, nullptr, DIM, DIM, 1.f, VT,
        nullptr);

    // QK^T: 3-way split (hi.hi + hi.lo + lo.hi; lo.lo ~4e-4 scaled, dropped)
    gemm256<3><<<256, 512, 0, stream>>>(
        Qhi, Khi, Qhi, Klo, Qlo, Khi, SEQ, DIM, 0.03125f, S);

    softmax_rows<<<SEQ, 256, 0, stream>>>(S, P);

    gemm_bt<EPI_F32, 1><<<pgrid, 256, 0, stream>>>(
        P, VT, nullptr, nullptr, nullptr, nullptr, DIM, SEQ, 1.f, O, nullptr);
}

// Round 5
// 282.742 us; speedup vs baseline: 28.0187x; 1.3120x over previous
//
#include <hip/hip_runtime.h>
#include <math.h>

#define SEQ 4096
#define DIM 1024

typedef __bf16 bf16;
typedef __bf16 bf16x8 __attribute__((ext_vector_type(8)));
typedef __bf16 bf16x4 __attribute__((ext_vector_type(4)));
typedef float f32x4 __attribute__((ext_vector_type(4)));

#define GLOAD_LDS16(g, l)                                              \
    __builtin_amdgcn_global_load_lds(                                  \
        (const __attribute__((address_space(1))) void*)(g),            \
        (__attribute__((address_space(3))) void*)(l), 16, 0, 0)

// ---------------------------------------------------------------------------
// Split f32 -> (hi, lo) bf16, vectorized by 4.
// ---------------------------------------------------------------------------
__global__ __launch_bounds__(256) void split_f32(const float* __restrict__ in,
                                                 bf16* __restrict__ hi,
                                                 bf16* __restrict__ lo, int n4) {
    const int i = blockIdx.x * 256 + threadIdx.x;
    if (i >= n4) return;
    const float4 v = ((const float4*)in)[i];
    const float vv[4] = {v.x, v.y, v.z, v.w};
    bf16x4 h, l;
#pragma unroll
    for (int q = 0; q < 4; ++q) {
        const bf16 hq = (bf16)vv[q];
        h[q] = hq;
        l[q] = (bf16)(vv[q] - (float)hq);
    }
    ((bf16x4*)hi)[i] = h;
    ((bf16x4*)lo)[i] = l;
}

// ---------------------------------------------------------------------------
// Transpose-convert W [DIM][DIM] f32 -> W^T bf16 (hi, and lo if SPLIT).
// ---------------------------------------------------------------------------
template <bool SPLIT>
__global__ __launch_bounds__(256) void wtrans(const float* __restrict__ W,
                                              bf16* __restrict__ hiT,
                                              bf16* __restrict__ loT) {
    __shared__ float tile[32][33];
    const int tid = threadIdx.x;
    const int r0 = blockIdx.x * 32;  // W row (k)
    const int c0 = blockIdx.y * 32;  // W col (n)
    {
        const int r = tid >> 3, c = (tid & 7) * 4;
        const float4 v = *(const float4*)&W[(size_t)(r0 + r) * DIM + c0 + c];
        tile[r][c + 0] = v.x;
        tile[r][c + 1] = v.y;
        tile[r][c + 2] = v.z;
        tile[r][c + 3] = v.w;
    }
    __syncthreads();
    {
        const int n = tid >> 3;
        const int k = (tid & 7) * 4;
        bf16x4 h, l;
#pragma unroll
        for (int q = 0; q < 4; ++q) {
            const float x = tile[k + q][n];
            const bf16 hq = (bf16)x;
            h[q] = hq;
            if (SPLIT) l[q] = (bf16)(x - (float)hq);
        }
        *(bf16x4*)&hiT[(size_t)(c0 + n) * DIM + r0 + k] = h;
        if (SPLIT) *(bf16x4*)&loT[(size_t)(c0 + n) * DIM + r0 + k] = l;
    }
}

// ---------------------------------------------------------------------------
// Unified 128x128 MFMA GEMM, BK=64, 256 thr (4 waves 2x2, wave tile 64x64),
// double-buffered LDS (64 KB -> 2 blocks/CU) with counted-vmcnt prefetch
// (never vmcnt(0) in the loop), XOR-swizzled LDS (linear gload_lds dest +
// pre-swizzled global source + swizzled read), XCD-aware block swizzle.
// C(Mx N) = sum_p A_p [M][K] @ B_p^T [N][K];  K = KTILES*64.
// Optional merged dispatch: blocks with by >= ysplit use the "b" pointer set.
// ---------------------------------------------------------------------------
#define EPI_F32 0
#define EPI_SPLIT 1
#define EPI_TRANS 2

template <int EPI, int NPAIR, int KTILES>
__global__ __launch_bounds__(256, 2) void gemm128p(
    const bf16* __restrict__ A0, const bf16* __restrict__ A1,
    const bf16* __restrict__ A2,
    const bf16* __restrict__ B0a, const bf16* __restrict__ B1a,
    const bf16* __restrict__ B2a,
    const bf16* __restrict__ B0b, const bf16* __restrict__ B1b,
    const bf16* __restrict__ B2b,
    int ysplit, int N, float scale,
    void* out0a, void* out1a, void* out0b, void* out1b) {
    constexpr int K = KTILES * 64;
    __shared__ __align__(16) bf16 As[2][128 * 64];   // 32 KB
    __shared__ __align__(16) bf16 Bs[2][128 * 64];   // 32 KB

    const int tid = threadIdx.x;
    const int lane = tid & 63;
    const int wid = tid >> 6;
    const int wr = wid >> 1, wc = wid & 1;

    // XCD-aware bijective swizzle (gridDim.x == 32 in all launches;
    // total blocks always divisible by 8).
    const int total = (int)(gridDim.y << 5);
    int lid = (int)blockIdx.y * 32 + (int)blockIdx.x;
    lid = (lid & 7) * (total >> 3) + (lid >> 3);
    const int bx = lid & 31;
    int by = lid >> 5;

    const bf16 *B0, *B1, *B2;
    void *o0, *o1;
    if (by >= ysplit) {
        by -= ysplit;
        B0 = B0b; B1 = B1b; B2 = B2b;
        o0 = out0b; o1 = out1b;
    } else {
        B0 = B0a; B1 = B1a; B2 = B2a;
        o0 = out0a; o1 = out1a;
    }
    const int m0 = bx * 128;
    const int n0 = by * 128;

    const bf16* APs[3] = {A0, A1, A2};
    const bf16* BPs[3] = {B0, B1, B2};
    const int nt = NPAIR * KTILES;

    f32x4 acc[4][4];
#pragma unroll
    for (int i = 0; i < 4; ++i)
#pragma unroll
        for (int j = 0; j < 4; ++j) acc[i][j] = (f32x4){0.f, 0.f, 0.f, 0.f};

    // Stage one 128x64 K-tile of A and B into buffer b (8 gload_lds/thread).
    // LDS dest linear; global source col XOR-pre-swizzled (involution with
    // the swizzled read below).
    auto STAGE = [&](int t, int b) {
        const int pass = t / KTILES;
        const int k0 = (t % KTILES) * 64;
        const bf16* Ap = APs[pass];
        const bf16* Bp = BPs[pass];
#pragma unroll
        for (int L = 0; L < 4; ++L) {
            const int idx = L * 256 + tid;          // 16B slot index (0..1023)
            const int row = idx >> 3;               // 0..127
            const int sc = ((idx & 7) * 16) ^ ((row & 7) << 4);  // src col-byte
            const int ldsu = (L * 256 + (tid & ~63)) * 8;        // uniform elems
            GLOAD_LDS16(Ap + (size_t)(m0 + row) * K + k0 + (sc >> 1),
                        &As[b][ldsu]);
            GLOAD_LDS16(Bp + (size_t)(n0 + row) * K + k0 + (sc >> 1),
                        &Bs[b][ldsu]);
        }
    };

    STAGE(0, 0);

    for (int t = 0; t < nt; ++t) {
        const int cur = t & 1;
        // Barrier A: all waves finished reading buf cur^1 (iter t-1 body).
        __builtin_amdgcn_s_barrier();
        asm volatile("" ::: "memory");
        if (t + 1 < nt) {
            STAGE(t + 1, cur ^ 1);
            asm volatile("s_waitcnt vmcnt(8)" ::: "memory");  // STAGE(t) done
        } else {
            asm volatile("s_waitcnt vmcnt(0)" ::: "memory");
        }
        // Barrier B: everyone's STAGE(t) writes visible.
        __builtin_amdgcn_s_barrier();
        asm volatile("" ::: "memory");

#pragma unroll
        for (int kk = 0; kk < 2; ++kk) {
            const int cb = kk * 64 + (lane >> 4) * 16;  // col-byte of fragment
            bf16x8 af[4], bv[4];
#pragma unroll
            for (int i = 0; i < 4; ++i) {
                const int r = wr * 64 + i * 16 + (lane & 15);
                af[i] = *(const bf16x8*)(&As[cur][r * 64 +
                                                  ((cb ^ ((r & 7) << 4)) >> 1)]);
            }
#pragma unroll
            for (int j = 0; j < 4; ++j) {
                const int r = wc * 64 + j * 16 + (lane & 15);
                bv[j] = *(const bf16x8*)(&Bs[cur][r * 64 +
                                                  ((cb ^ ((r & 7) << 4)) >> 1)]);
            }
            __builtin_amdgcn_s_setprio(1);
#pragma unroll
            for (int i = 0; i < 4; ++i)
#pragma unroll
                for (int j = 0; j < 4; ++j)
                    acc[i][j] = __builtin_amdgcn_mfma_f32_16x16x32_bf16(
                        af[i], bv[j], acc[i][j], 0, 0, 0);
            __builtin_amdgcn_s_setprio(0);
        }
    }

    // Epilogue. acc[i][j][q] = C[m0+wr*64+i*16+(lane>>4)*4+q][n0+wc*64+j*16+(lane&15)]
    const int row0 = m0 + wr * 64 + (lane >> 4) * 4;
    const int col0 = n0 + wc * 64 + (lane & 15);

    if (EPI == EPI_F32) {
        float* O = (float*)o0;
#pragma unroll
        for (int i = 0; i < 4; ++i)
#pragma unroll
            for (int j = 0; j < 4; ++j)
#pragma unroll
                for (int q = 0; q < 4; ++q)
                    O[(size_t)(row0 + i * 16 + q) * N + col0 + j * 16] =
                        acc[i][j][q] * scale;
    } else if (EPI == EPI_SPLIT) {
        bf16* Hi = (bf16*)o0;
        bf16* Lo = (bf16*)o1;
#pragma unroll
        for (int i = 0; i < 4; ++i)
#pragma unroll
            for (int j = 0; j < 4; ++j)
#pragma unroll
                for (int q = 0; q < 4; ++q) {
                    const float x = acc[i][j][q];
                    const bf16 h = (bf16)x;
                    const size_t idx = (size_t)(row0 + i * 16 + q) * N + col0 + j * 16;
                    Hi[idx] = h;
                    Lo[idx] = (bf16)(x - (float)h);
                }
    } else {  // EPI_TRANS: out[col][row] over SEQ rows
        bf16* OT = (bf16*)o0;
#pragma unroll
        for (int i = 0; i < 4; ++i)
#pragma unroll
            for (int j = 0; j < 4; ++j) {
                bf16x4 v;
#pragma unroll
                for (int q = 0; q < 4; ++q) v[q] = (bf16)acc[i][j][q];
                *(bf16x4*)&OT[(size_t)(col0 + j * 16) * SEQ + row0 + i * 16] = v;
            }
    }
}

// ---------------------------------------------------------------------------
// Row softmax: S (f32 [SEQ][SEQ], already scaled) -> P (bf16, normalized).
// ---------------------------------------------------------------------------
__global__ __launch_bounds__(256) void softmax_rows(const float* __restrict__ S,
                                                    bf16* __restrict__ P) {
    __shared__ float red[8];
    const int tid = threadIdx.x;
    const size_t row = blockIdx.x;
    const float4* s4 = (const float4*)(S + row * SEQ);

    float4 v[4];
    float mx = -1e30f;
#pragma unroll
    for (int c = 0; c < 4; ++c) {
        v[c] = s4[c * 256 + tid];
        mx = fmaxf(mx, fmaxf(fmaxf(v[c].x, v[c].y), fmaxf(v[c].z, v[c].w)));
    }
#pragma unroll
    for (int m = 32; m >= 1; m >>= 1) mx = fmaxf(mx, __shfl_xor(mx, m));
    if ((tid & 63) == 0) red[tid >> 6] = mx;
    __syncthreads();
    mx = fmaxf(fmaxf(red[0], red[1]), fmaxf(red[2], red[3]));

    float e[16];
    float sum = 0.f;
#pragma unroll
    for (int c = 0; c < 4; ++c) {
        e[c * 4 + 0] = __expf(v[c].x - mx);
        e[c * 4 + 1] = __expf(v[c].y - mx);
        e[c * 4 + 2] = __expf(v[c].z - mx);
        e[c * 4 + 3] = __expf(v[c].w - mx);
        sum += e[c * 4] + e[c * 4 + 1] + e[c * 4 + 2] + e[c * 4 + 3];
    }
#pragma unroll
    for (int m = 32; m >= 1; m >>= 1) sum += __shfl_xor(sum, m);
    if ((tid & 63) == 0) red[4 + (tid >> 6)] = sum;
    __syncthreads();
    sum = red[4] + red[5] + red[6] + red[7];
    const float inv = 1.f / sum;

    bf16* prow = P + row * SEQ;
#pragma unroll
    for (int c = 0; c < 4; ++c) {
        bf16x4 o;
#pragma unroll
        for (int q = 0; q < 4; ++q) o[q] = (bf16)(e[c * 4 + q] * inv);
        ((bf16x4*)prow)[c * 256 + tid] = o;
    }
}

// ---------------------------------------------------------------------------
extern "C" void kernel_launch(void* const* d_in, const int* in_sizes, int n_in,
                              void* d_out, int out_size, void* d_ws, size_t ws_size,
                              hipStream_t stream) {
    const float* x  = (const float*)d_in[0];
    const float* wq = (const float*)d_in[1];
    const float* wk = (const float*)d_in[2];
    const float* wv = (const float*)d_in[3];
    float* O = (float*)d_out;

    char* ws = (char*)d_ws;
    const size_t MB = 1024 * 1024;
    bf16* Qhi = (bf16*)(ws + 0 * MB);
    bf16* Qlo = (bf16*)(ws + 8 * MB);
    bf16* Khi = (bf16*)(ws + 16 * MB);
    bf16* Klo = (bf16*)(ws + 24 * MB);
    bf16* VT  = (bf16*)(ws + 32 * MB);
    float* S  = (float*)(ws + 40 * MB);   // 64 MB
    bf16* P   = (bf16*)(ws + 0 * MB);     // overlays dead Q/K
    bf16* Xhi   = (bf16*)(ws + 40 * MB);  // converts die before S written
    bf16* Xlo   = (bf16*)(ws + 48 * MB);
    bf16* WqhiT = (bf16*)(ws + 56 * MB);
    bf16* WqloT = (bf16*)(ws + 58 * MB);
    bf16* WkhiT = (bf16*)(ws + 60 * MB);
    bf16* WkloT = (bf16*)(ws + 62 * MB);
    bf16* WvT   = (bf16*)(ws + 64 * MB);

    split_f32<<<(SEQ * DIM / 4 + 255) / 256, 256, 0, stream>>>(x, Xhi, Xlo,
                                                               SEQ * DIM / 4);
    const dim3 wgrid(DIM / 32, DIM / 32);
    wtrans<true><<<wgrid, 256, 0, stream>>>(wq, WqhiT, WqloT);
    wtrans<true><<<wgrid, 256, 0, stream>>>(wk, WkhiT, WkloT);
    wtrans<false><<<wgrid, 256, 0, stream>>>(wv, WvT, nullptr);

    // Q and K projections merged in one dispatch (by<8 -> Q, by>=8 -> K).
    gemm128p<EPI_SPLIT, 3, 16><<<dim3(32, 16), 256, 0, stream>>>(
        Xhi, Xhi, Xlo,
        WqhiT, WqloT, WqhiT,
        WkhiT, WkloT, WkhiT,
        8, DIM, 1.f, Qhi, Qlo, Khi, Klo);

    // V projection (transposed bf16 store).
    gemm128p<EPI_TRANS, 1, 16><<<dim3(32, 8), 256, 0, stream>>>(
        Xhi, Xhi, Xhi,
        WvT, WvT, WvT,
        WvT, WvT, WvT,
        8, DIM, 1.f, VT, nullptr, VT, nullptr);

    // QK^T: 3-way split (hi.hi + hi.lo + lo.hi), scaled, f32 out.
    gemm128p<EPI_F32, 3, 16><<<dim3(32, 32), 256, 0, stream>>>(
        Qhi, Qhi, Qlo,
        Khi, Klo, Khi,
        Khi, Klo, Khi,
        32, SEQ, 0.03125f, S, nullptr, S, nullptr);

    softmax_rows<<<SEQ, 256, 0, stream>>>(S, P);

    // O = P @ V  (B^T = VT), K = SEQ.
    gemm128p<EPI_F32, 1, 64><<<dim3(32, 8), 256, 0, stream>>>(
        P, P, P,
        VT, VT, VT,
        VT, VT, VT,
        8, DIM, 1.f, O, nullptr, O, nullptr);
}